// Round 2
// baseline (214.813 us; speedup 1.0000x reference)
//
#include <hip/hip_runtime.h>
#include <hip/hip_bf16.h>
#include <stdint.h>

#define BATCH 16
#define CIN   512
#define COUT  512
#define HH    32
#define WW    32
#define HP    34          // padded spatial (32 + 2)
#define HWN   1024        // 32*32
#define EPS_  1e-8f

typedef __attribute__((ext_vector_type(8))) short bf16x8;   // 8 bf16 = 4 VGPR (guide §3)
typedef __attribute__((ext_vector_type(4))) float f32x4;
typedef __attribute__((address_space(1))) void gvoid;       // global
typedef __attribute__((address_space(3))) void lvoid;       // LDS

// ---- workspace layout (bytes) ----
// xs_pad bf16 [B][34][34][CIN] (NHWC, zero borders) : 18,939,904
// Wt     bf16 [9][COUT][CIN]  (tap-major)           :  4,718,592
// wsq    f32  [COUT][CIN]                           :  1,048,576
// isg    f32  [B][COUT]  (1/sigma)                  :     32,768
// total ~24.8 MB
#define XS_OFF    0
#define XS_BYTES  (BATCH*HP*HP*CIN*2)
#define WT_OFF    (XS_OFF + XS_BYTES)
#define WT_BYTES  (9*COUT*CIN*2)
#define WSQ_OFF   (WT_OFF + WT_BYTES)
#define WSQ_BYTES (COUT*CIN*4)
#define ISG_OFF   (WSQ_OFF + WSQ_BYTES)

// K1: wsq[o,i] = sum_k w[o,i,k]^2 ; Wt[k][o][i] = bf16(w[o,i,k])
__global__ void prep_weight(const float* __restrict__ w,
                            __hip_bfloat16* __restrict__ wt,
                            float* __restrict__ wsq) {
  int idx = blockIdx.x * 256 + threadIdx.x;     // idx = o*512 + i
  if (idx >= COUT * CIN) return;
  const float* wp = w + (size_t)idx * 9;
  float ss = 0.f;
#pragma unroll
  for (int k = 0; k < 9; ++k) {
    float v = wp[k];
    ss += v * v;
    wt[(size_t)k * COUT * CIN + idx] = __float2bfloat16(v);
  }
  wsq[idx] = ss;
}

// K2: isg[b,o] = 1/sqrt( sum_i s[b,i]^2 * wsq[o,i] + eps )
__global__ void calc_isig(const float* __restrict__ s,
                          const float* __restrict__ wsq,
                          float* __restrict__ isg) {
  int b = blockIdx.x >> 9;
  int o = blockIdx.x & 511;
  int l = threadIdx.x;                           // 64 threads = 1 wave
  const float* sp = s + b * CIN;
  const float* wq = wsq + o * CIN;
  float acc = 0.f;
  for (int i = l; i < CIN; i += 64) {
    float sv = sp[i];
    acc += sv * sv * wq[i];
  }
#pragma unroll
  for (int off = 32; off; off >>= 1) acc += __shfl_xor(acc, off);
  if (l == 0) isg[blockIdx.x] = 1.0f / sqrtf(acc + EPS_);
}

// K3: xs_pad[b][hp][wp][i] = bf16( s[b,i] * x[b,i,hp-1,wp-1] ), zeros on border.
// One thread per (b,hp,wp, 8-wide i chunk): coalesced 16B writes.
__global__ void pack_x(const float* __restrict__ x,
                       const float* __restrict__ s,
                       __hip_bfloat16* __restrict__ xs) {
  int t = blockIdx.x * 256 + threadIdx.x;
  if (t >= BATCH * HP * HP * 64) return;
  int ic = t & 63;
  int pos = t >> 6;                              // b*34*34 + hp*34 + wp
  int wp = pos % HP;
  int tmp = pos / HP;
  int hp = tmp % HP;
  int b  = tmp / HP;
  int4* dst = (int4*)(xs + (size_t)pos * CIN + ic * 8);
  int h = hp - 1, w = wp - 1;
  if ((unsigned)h < 32u && (unsigned)w < 32u) {
    const float* xp = x + (size_t)b * CIN * HWN + h * WW + w;
    const float* sp = s + b * CIN + ic * 8;
    union { short sh[8]; int4 v; } u;
#pragma unroll
    for (int j = 0; j < 8; ++j) {
      int i = ic * 8 + j;
      float v = xp[(size_t)i * HWN] * sp[j];
      __hip_bfloat16 hb = __float2bfloat16(v);
      u.sh[j] = *reinterpret_cast<short*>(&hb);
    }
    *dst = u.v;
  } else {
    *dst = make_int4(0, 0, 0, 0);
  }
}

// K4: implicit-GEMM conv. Per batch: C[512 x 1024] = Wt(tap-major) @ patches,
// K = 9 taps x 512 ci. 128x128 tile, BK=64, 4 waves (2x2), 16x16x32 bf16 MFMA.
// LDS tiles [row][64 bf16] with XOR-chunk swizzle; staged via global_load_lds
// width=16 with inverse-swizzled global source (both-sides-or-neither rule).
__global__ __launch_bounds__(256, 2)
void conv_mfma(const __hip_bfloat16* __restrict__ xs,
               const __hip_bfloat16* __restrict__ wt,
               const float* __restrict__ isg,
               float* __restrict__ out) {
  __shared__ __align__(16) char lds[32768];
  char* ldsA = lds;                // [128 rows][128 B]  (o-major,  k contig)
  char* ldsB = lds + 16384;        // [128 rows][128 B]  (hw-major, k contig)

  const int bid = blockIdx.x;
  const int nt = bid & 7;          // hw tile
  const int mt = (bid >> 3) & 3;   // o tile
  const int b  = bid >> 5;         // batch
  const int m0  = mt * 128;
  const int hw0 = nt * 128;

  const int t  = threadIdx.x;
  const int wv = t >> 6;
  const int l  = t & 63;
  const int wr = wv >> 1;          // wave row in 2x2 (o dim, 64 each)
  const int wc = wv & 1;           // wave col (hw dim, 64 each)
  const int segbase = wv * 4;

  // staging: per thread 4 segments each for A and B; 16B per lane per instr.
  // LDS row r = seg*8 + (l>>3); LDS chunk slot = l&7 holds global chunk (l&7)^(r&7).
  int baseA[4], baseB[4];
#pragma unroll
  for (int q = 0; q < 4; ++q) {
    int seg = segbase + q;
    int r = seg * 8 + (l >> 3);
    int swz = (l & 7) ^ (l >> 3);                   // (l&7) ^ (r&7)
    baseA[q] = (m0 + r) * CIN + swz * 8;            // elements into Wt[tap] plane
    int n_abs = hw0 + r;
    int hB = n_abs >> 5, wB = n_abs & 31;
    baseB[q] = ((b * HP + hB) * HP + wB) * CIN + swz * 8;  // + (kh*HP+kw)*CIN + i0
  }

  // MFMA fragment ds_read_b128 byte offsets (constant across K loop).
  // row = tilebase + f*16 + (l&15); global chunk cg = kk*4 + (l>>4);
  // slot = cg ^ (row&7) = cg ^ (l&7).
  int offA[2][4], offB[2][4];
#pragma unroll
  for (int kk = 0; kk < 2; ++kk) {
#pragma unroll
    for (int f = 0; f < 4; ++f) {
      int slot = ((kk * 4) + (l >> 4)) ^ (l & 7);
      offA[kk][f] = (wr * 64 + f * 16 + (l & 15)) * 128 + slot * 16;
      offB[kk][f] = (wc * 64 + f * 16 + (l & 15)) * 128 + slot * 16;
    }
  }

  f32x4 acc[4][4];
#pragma unroll
  for (int m = 0; m < 4; ++m)
#pragma unroll
    for (int n = 0; n < 4; ++n)
      acc[m][n] = (f32x4){0.f, 0.f, 0.f, 0.f};

  for (int kh = 0; kh < 3; ++kh) {
    for (int kw = 0; kw < 3; ++kw) {
      const int uA0 = (kh * 3 + kw) * COUT * CIN;   // tap plane in Wt
      const int uB0 = (kh * HP + kw) * CIN;         // spatial shift in xs_pad
      for (int ic = 0; ic < 8; ++ic) {
        const int i0 = ic * 64;
#pragma unroll
        for (int q = 0; q < 4; ++q)
          __builtin_amdgcn_global_load_lds(
              (gvoid*)(const void*)(wt + uA0 + i0 + baseA[q]),
              (lvoid*)(ldsA + (segbase + q) * 1024), 16, 0, 0);
#pragma unroll
        for (int q = 0; q < 4; ++q)
          __builtin_amdgcn_global_load_lds(
              (gvoid*)(const void*)(xs + uB0 + i0 + baseB[q]),
              (lvoid*)(ldsB + (segbase + q) * 1024), 16, 0, 0);
        __syncthreads();                             // drains vmcnt + lgkm
#pragma unroll
        for (int kk = 0; kk < 2; ++kk) {
          bf16x8 af[4], bfr[4];
#pragma unroll
          for (int f = 0; f < 4; ++f) af[f]  = *(const bf16x8*)(ldsA + offA[kk][f]);
#pragma unroll
          for (int f = 0; f < 4; ++f) bfr[f] = *(const bf16x8*)(ldsB + offB[kk][f]);
#pragma unroll
          for (int m = 0; m < 4; ++m)
#pragma unroll
            for (int n = 0; n < 4; ++n)
              acc[m][n] = __builtin_amdgcn_mfma_f32_16x16x32_bf16(
                  af[m], bfr[n], acc[m][n], 0, 0, 0);
        }
        __syncthreads();                             // protect next stage
      }
    }
  }

  // epilogue: out[b][o][hw] = acc * isg[b][o]   (C/D: col=l&15 -> hw, row=(l>>4)*4+j -> o)
#pragma unroll
  for (int m = 0; m < 4; ++m) {
#pragma unroll
    for (int j = 0; j < 4; ++j) {
      int o = m0 + wr * 64 + m * 16 + (l >> 4) * 4 + j;
      float sg = isg[b * COUT + o];
      float* orow = out + ((size_t)(b * COUT + o)) * HWN + hw0 + wc * 64 + (l & 15);
#pragma unroll
      for (int n = 0; n < 4; ++n)
        orow[n * 16] = acc[m][n][j] * sg;
    }
  }
}

extern "C" void kernel_launch(void* const* d_in, const int* in_sizes, int n_in,
                              void* d_out, int out_size, void* d_ws, size_t ws_size,
                              hipStream_t stream) {
  const float* x = (const float*)d_in[0];
  const float* s = (const float*)d_in[1];
  const float* w = (const float*)d_in[2];
  float* out = (float*)d_out;
  char* ws = (char*)d_ws;
  __hip_bfloat16* xs  = (__hip_bfloat16*)(ws + XS_OFF);
  __hip_bfloat16* wt  = (__hip_bfloat16*)(ws + WT_OFF);
  float*          wsq = (float*)(ws + WSQ_OFF);
  float*          isg = (float*)(ws + ISG_OFF);

  hipLaunchKernelGGL(prep_weight, dim3((COUT * CIN + 255) / 256), dim3(256), 0, stream,
                     w, wt, wsq);
  hipLaunchKernelGGL(pack_x, dim3((BATCH * HP * HP * 64 + 255) / 256), dim3(256), 0, stream,
                     x, s, xs);
  hipLaunchKernelGGL(calc_isig, dim3(BATCH * COUT), dim3(64), 0, stream,
                     s, wsq, isg);
  hipLaunchKernelGGL(conv_mfma, dim3(BATCH * 4 * 8), dim3(256), 0, stream,
                     xs, wt, isg, out);
}

// Round 3
// 176.189 us; speedup vs baseline: 1.2192x; 1.2192x over previous
//
#include <hip/hip_runtime.h>
#include <hip/hip_bf16.h>
#include <stdint.h>

#define BATCH 16
#define CIN   512
#define COUT  512
#define HH    32
#define WW    32
#define HP    34          // padded spatial (32 + 2)
#define HWN   1024        // 32*32
#define EPS_  1e-8f

typedef __attribute__((ext_vector_type(8))) short bf16x8;   // 8 bf16 = 4 VGPR
typedef __attribute__((ext_vector_type(4))) float f32x4;
typedef __attribute__((address_space(1))) void gvoid;       // global
typedef __attribute__((address_space(3))) void lvoid;       // LDS

// ---- workspace layout (bytes) ----
// xs_pad bf16 [B][34][34][CIN] (NHWC, zero borders) : 18,939,904
// Wt     bf16 [9][COUT][CIN]  (tap-major)           :  4,718,592
// wsq    f32  [COUT][CIN]                           :  1,048,576
// isg    f32  [B][COUT]  (1/sigma)                  :     32,768
// total ~24.8 MB
#define XS_OFF    0
#define XS_BYTES  (BATCH*HP*HP*CIN*2)
#define WT_OFF    (XS_OFF + XS_BYTES)
#define WT_BYTES  (9*COUT*CIN*2)
#define WSQ_OFF   (WT_OFF + WT_BYTES)
#define WSQ_BYTES (COUT*CIN*4)
#define ISG_OFF   (WSQ_OFF + WSQ_BYTES)

// K1: wsq[o,i] = sum_k w[o,i,k]^2 ; Wt[k][o][i] = bf16(w[o,i,k])
__global__ void prep_weight(const float* __restrict__ w,
                            __hip_bfloat16* __restrict__ wt,
                            float* __restrict__ wsq) {
  int idx = blockIdx.x * 256 + threadIdx.x;     // idx = o*512 + i
  if (idx >= COUT * CIN) return;
  const float* wp = w + (size_t)idx * 9;
  float ss = 0.f;
#pragma unroll
  for (int k = 0; k < 9; ++k) {
    float v = wp[k];
    ss += v * v;
    wt[(size_t)k * COUT * CIN + idx] = __float2bfloat16(v);
  }
  wsq[idx] = ss;
}

// K2: isg[b,o] = 1/sqrt( sum_i s[b,i]^2 * wsq[o,i] + eps )
__global__ void calc_isig(const float* __restrict__ s,
                          const float* __restrict__ wsq,
                          float* __restrict__ isg) {
  int b = blockIdx.x >> 9;
  int o = blockIdx.x & 511;
  int l = threadIdx.x;                           // 64 threads = 1 wave
  const float* sp = s + b * CIN;
  const float* wq = wsq + o * CIN;
  float acc = 0.f;
  for (int i = l; i < CIN; i += 64) {
    float sv = sp[i];
    acc += sv * sv * wq[i];
  }
#pragma unroll
  for (int off = 32; off; off >>= 1) acc += __shfl_xor(acc, off);
  if (l == 0) isg[blockIdx.x] = 1.0f / sqrtf(acc + EPS_);
}

// K3a: zero the padded border of xs: positions where hp in {0,33} or wp in {0,33}.
// 132 border positions per batch, 512 bf16 = 64 int4 each -> 64 threads/block.
__global__ void zero_borders(__hip_bfloat16* __restrict__ xs) {
  int e = blockIdx.x % 132;
  int b = blockIdx.x / 132;
  int l = threadIdx.x;
  int hp, wp;
  if (e < 34)      { hp = 0;  wp = e; }
  else if (e < 68) { hp = 33; wp = e - 34; }
  else { int f = e - 68; hp = 1 + (f >> 1); wp = (f & 1) ? 33 : 0; }
  int4* dst = (int4*)(xs + (((size_t)(b * HP + hp)) * HP + wp) * CIN);
  dst[l] = make_int4(0, 0, 0, 0);
}

// K3b: interior pack+transpose. One block per (b,h): reads x[b,:,h,:]
// coalesced (float4 along w), scales by s[b,i], LDS write-transpose to
// [w][i], then fully coalesced 16B stores to xs[b][h+1][w+1][i].
__global__ __launch_bounds__(256)
void pack_x2(const float* __restrict__ x,
             const float* __restrict__ s,
             __hip_bfloat16* __restrict__ xs) {
  __shared__ unsigned short tile[32][520];   // [w][i], +8 pad
  __shared__ float ssh[CIN];
  const int bid = blockIdx.x;
  const int h = bid & 31;
  const int b = bid >> 5;
  const int tid = threadIdx.x;

  ssh[tid]       = s[b * CIN + tid];
  ssh[256 + tid] = s[b * CIN + 256 + tid];
  __syncthreads();

  const int r = tid >> 3;                    // i sub-row 0..31
  const int c = tid & 7;                     // float4 col 0..7
  const float* xbase = x + (size_t)b * CIN * HWN + h * WW;   // + i*HWN + w
#pragma unroll
  for (int p = 0; p < 16; ++p) {
    int i = p * 32 + r;
    float4 v = *(const float4*)(xbase + (size_t)i * HWN + c * 4);
    float sc = ssh[i];
#pragma unroll
    for (int j = 0; j < 4; ++j) {
      float f = ((const float*)&v)[j] * sc;
      __hip_bfloat16 hb = __float2bfloat16(f);
      tile[c * 4 + j][i] = *(unsigned short*)&hb;
    }
  }
  __syncthreads();

  const int w  = tid >> 3;                   // 0..31
  const int i0 = (tid & 7) * 64;             // 8 chunks of 64 bf16 (128B)
  __hip_bfloat16* dst = xs + (((size_t)(b * HP + h + 1)) * HP + (w + 1)) * CIN + i0;
  const int4* src = (const int4*)&tile[w][i0];
#pragma unroll
  for (int q = 0; q < 8; ++q)
    ((int4*)dst)[q] = src[q];
}

// K4: implicit-GEMM conv (unchanged from round 2 — verified 910 TF, 0 bank conflicts).
__global__ __launch_bounds__(256, 2)
void conv_mfma(const __hip_bfloat16* __restrict__ xs,
               const __hip_bfloat16* __restrict__ wt,
               const float* __restrict__ isg,
               float* __restrict__ out) {
  __shared__ __align__(16) char lds[32768];
  char* ldsA = lds;                // [128 rows][128 B]  (o-major,  k contig)
  char* ldsB = lds + 16384;        // [128 rows][128 B]  (hw-major, k contig)

  const int bid = blockIdx.x;
  const int nt = bid & 7;          // hw tile
  const int mt = (bid >> 3) & 3;   // o tile
  const int b  = bid >> 5;         // batch
  const int m0  = mt * 128;
  const int hw0 = nt * 128;

  const int t  = threadIdx.x;
  const int wv = t >> 6;
  const int l  = t & 63;
  const int wr = wv >> 1;          // wave row in 2x2 (o dim, 64 each)
  const int wc = wv & 1;           // wave col (hw dim, 64 each)
  const int segbase = wv * 4;

  int baseA[4], baseB[4];
#pragma unroll
  for (int q = 0; q < 4; ++q) {
    int seg = segbase + q;
    int r = seg * 8 + (l >> 3);
    int swz = (l & 7) ^ (l >> 3);                   // (l&7) ^ (r&7)
    baseA[q] = (m0 + r) * CIN + swz * 8;
    int n_abs = hw0 + r;
    int hB = n_abs >> 5, wB = n_abs & 31;
    baseB[q] = ((b * HP + hB) * HP + wB) * CIN + swz * 8;
  }

  int offA[2][4], offB[2][4];
#pragma unroll
  for (int kk = 0; kk < 2; ++kk) {
#pragma unroll
    for (int f = 0; f < 4; ++f) {
      int slot = ((kk * 4) + (l >> 4)) ^ (l & 7);
      offA[kk][f] = (wr * 64 + f * 16 + (l & 15)) * 128 + slot * 16;
      offB[kk][f] = (wc * 64 + f * 16 + (l & 15)) * 128 + slot * 16;
    }
  }

  f32x4 acc[4][4];
#pragma unroll
  for (int m = 0; m < 4; ++m)
#pragma unroll
    for (int n = 0; n < 4; ++n)
      acc[m][n] = (f32x4){0.f, 0.f, 0.f, 0.f};

  for (int kh = 0; kh < 3; ++kh) {
    for (int kw = 0; kw < 3; ++kw) {
      const int uA0 = (kh * 3 + kw) * COUT * CIN;
      const int uB0 = (kh * HP + kw) * CIN;
      for (int ic = 0; ic < 8; ++ic) {
        const int i0 = ic * 64;
#pragma unroll
        for (int q = 0; q < 4; ++q)
          __builtin_amdgcn_global_load_lds(
              (gvoid*)(const void*)(wt + uA0 + i0 + baseA[q]),
              (lvoid*)(ldsA + (segbase + q) * 1024), 16, 0, 0);
#pragma unroll
        for (int q = 0; q < 4; ++q)
          __builtin_amdgcn_global_load_lds(
              (gvoid*)(const void*)(xs + uB0 + i0 + baseB[q]),
              (lvoid*)(ldsB + (segbase + q) * 1024), 16, 0, 0);
        __syncthreads();
#pragma unroll
        for (int kk = 0; kk < 2; ++kk) {
          bf16x8 af[4], bfr[4];
#pragma unroll
          for (int f = 0; f < 4; ++f) af[f]  = *(const bf16x8*)(ldsA + offA[kk][f]);
#pragma unroll
          for (int f = 0; f < 4; ++f) bfr[f] = *(const bf16x8*)(ldsB + offB[kk][f]);
#pragma unroll
          for (int m = 0; m < 4; ++m)
#pragma unroll
            for (int n = 0; n < 4; ++n)
              acc[m][n] = __builtin_amdgcn_mfma_f32_16x16x32_bf16(
                  af[m], bfr[n], acc[m][n], 0, 0, 0);
        }
        __syncthreads();
      }
    }
  }

#pragma unroll
  for (int m = 0; m < 4; ++m) {
#pragma unroll
    for (int j = 0; j < 4; ++j) {
      int o = m0 + wr * 64 + m * 16 + (l >> 4) * 4 + j;
      float sg = isg[b * COUT + o];
      float* orow = out + ((size_t)(b * COUT + o)) * HWN + hw0 + wc * 64 + (l & 15);
#pragma unroll
      for (int n = 0; n < 4; ++n)
        orow[n * 16] = acc[m][n][j] * sg;
    }
  }
}

extern "C" void kernel_launch(void* const* d_in, const int* in_sizes, int n_in,
                              void* d_out, int out_size, void* d_ws, size_t ws_size,
                              hipStream_t stream) {
  const float* x = (const float*)d_in[0];
  const float* s = (const float*)d_in[1];
  const float* w = (const float*)d_in[2];
  float* out = (float*)d_out;
  char* ws = (char*)d_ws;
  __hip_bfloat16* xs  = (__hip_bfloat16*)(ws + XS_OFF);
  __hip_bfloat16* wt  = (__hip_bfloat16*)(ws + WT_OFF);
  float*          wsq = (float*)(ws + WSQ_OFF);
  float*          isg = (float*)(ws + ISG_OFF);

  hipLaunchKernelGGL(prep_weight, dim3((COUT * CIN + 255) / 256), dim3(256), 0, stream,
                     w, wt, wsq);
  hipLaunchKernelGGL(zero_borders, dim3(BATCH * 132), dim3(64), 0, stream, xs);
  hipLaunchKernelGGL(pack_x2, dim3(BATCH * 32), dim3(256), 0, stream, x, s, xs);
  hipLaunchKernelGGL(calc_isig, dim3(BATCH * COUT), dim3(64), 0, stream,
                     s, wsq, isg);
  hipLaunchKernelGGL(conv_mfma, dim3(BATCH * 4 * 8), dim3(256), 0, stream,
                     xs, wt, isg, out);
}

// Round 5
// 170.189 us; speedup vs baseline: 1.2622x; 1.0353x over previous
//
#include <hip/hip_runtime.h>
#include <hip/hip_bf16.h>
#include <stdint.h>

#define BATCH 16
#define CIN   512
#define COUT  512
#define HH    32
#define WW    32
#define HP    34          // padded spatial (32 + 2)
#define HWN   1024        // 32*32
#define EPS_  1e-8f

#define NTILES 72         // 9 taps * 8 ic-chunks, BK=64
#define SLOTA  16384      // 128 rows * 128 B
#define SLOTB  32768      // 256 rows * 128 B
#define LDS_BYTES (3*(SLOTA+SLOTB))   // 147456

typedef __attribute__((ext_vector_type(8))) short bf16x8;
typedef __attribute__((ext_vector_type(4))) float f32x4;
typedef __attribute__((address_space(1))) void gvoid;
typedef __attribute__((address_space(3))) void lvoid;

// ---- workspace layout ----
#define XS_OFF    0
#define XS_BYTES  (BATCH*HP*HP*CIN*2)
#define WT_OFF    (XS_OFF + XS_BYTES)
#define WT_BYTES  (9*COUT*CIN*2)
#define ISG_OFF   (WT_OFF + WT_BYTES)

// K1: fused weight prep + demodulation sigma.
// One block per o: Wt[k][o][i]=bf16(w[o,i,k]); ss[i]=sum_k w^2;
// isg[b,o]=rsqrt(sum_i s[b,i]^2*ss[i]+eps) for all 16 b.
__global__ __launch_bounds__(256)
void wprep(const float* __restrict__ w, const float* __restrict__ s,
           __hip_bfloat16* __restrict__ wt, float* __restrict__ isg) {
  __shared__ float s2[BATCH * CIN];     // 32 KB
  __shared__ float red[16][4];
  const int o = blockIdx.x;
  const int t = threadIdx.x;

  for (int j = t; j < BATCH * CIN; j += 256) {
    float v = s[j];
    s2[j] = v * v;
  }

  float ss[2];
#pragma unroll
  for (int u = 0; u < 2; ++u) {
    int i = t + u * 256;
    const float* wp = w + ((size_t)o * CIN + i) * 9;
    float acc = 0.f;
#pragma unroll
    for (int k = 0; k < 9; ++k) {
      float v = wp[k];
      acc += v * v;
      __hip_bfloat16 hb = __float2bfloat16(v);
      wt[(size_t)k * COUT * CIN + o * CIN + i] = hb;
    }
    ss[u] = acc;
  }
  __syncthreads();

  float accb[16];
#pragma unroll
  for (int b = 0; b < 16; ++b) accb[b] = 0.f;
#pragma unroll
  for (int u = 0; u < 2; ++u) {
    int i = t + u * 256;
    float q = ss[u];
#pragma unroll
    for (int b = 0; b < 16; ++b) accb[b] += q * s2[b * CIN + i];
  }
#pragma unroll
  for (int b = 0; b < 16; ++b) {
#pragma unroll
    for (int off = 32; off; off >>= 1) accb[b] += __shfl_xor(accb[b], off);
    if ((t & 63) == 0) red[b][t >> 6] = accb[b];
  }
  __syncthreads();
  if (t < 16) {
    float tot = red[t][0] + red[t][1] + red[t][2] + red[t][3];
    isg[t * COUT + o] = 1.0f / sqrtf(tot + EPS_);
  }
}

// K2: pack+transpose with fused border zeroing. Grid B*34: hp row per block.
__global__ __launch_bounds__(256)
void pack3(const float* __restrict__ x, const float* __restrict__ s,
           __hip_bfloat16* __restrict__ xs) {
  const int bid = blockIdx.x;
  const int hp = bid % 34;
  const int b = bid / 34;
  const int tid = threadIdx.x;
  __hip_bfloat16* rowbase = xs + (((size_t)(b * HP + hp)) * HP) * CIN;

  if (hp == 0 || hp == 33) {            // full border row = 34*512 bf16 = 2176 int4
    for (int j = tid; j < HP * CIN / 8; j += 256)
      ((int4*)rowbase)[j] = make_int4(0, 0, 0, 0);
    return;
  }
  // side borders wp=0 / wp=33 (64 int4 each)
  if (tid < 64)        ((int4*)rowbase)[tid] = make_int4(0, 0, 0, 0);
  else if (tid < 128)  ((int4*)(rowbase + 33 * CIN))[tid - 64] = make_int4(0, 0, 0, 0);

  __shared__ unsigned short tile[32][520];   // [w][i], +8 pad
  __shared__ float ssh[CIN];
  ssh[tid]       = s[b * CIN + tid];
  ssh[256 + tid] = s[b * CIN + 256 + tid];
  __syncthreads();

  const int h = hp - 1;
  const int r = tid >> 3;
  const int c = tid & 7;
  const float* xbase = x + (size_t)b * CIN * HWN + h * WW;
#pragma unroll
  for (int p = 0; p < 16; ++p) {
    int i = p * 32 + r;
    float4 v = *(const float4*)(xbase + (size_t)i * HWN + c * 4);
    float sc = ssh[i];
#pragma unroll
    for (int j = 0; j < 4; ++j) {
      float f = ((const float*)&v)[j] * sc;
      __hip_bfloat16 hb = __float2bfloat16(f);
      tile[c * 4 + j][i] = *(unsigned short*)&hb;
    }
  }
  __syncthreads();

  const int wq = tid >> 3;
  const int i0 = (tid & 7) * 64;
  __hip_bfloat16* dst = rowbase + (wq + 1) * CIN + i0;
  const int4* src = (const int4*)&tile[wq][i0];
#pragma unroll
  for (int q = 0; q < 8; ++q)
    ((int4*)dst)[q] = src[q];
}

// K3: implicit-GEMM conv, 8-phase counted-vmcnt schedule (T3+T4+T5).
// BM=128 (o), BN=256 (hw), BK=64. 8 waves 2Mx4N, 64x64/wave. 256 blocks.
// 3 rotating LDS slots per matrix; tile t -> slot t%3; during tile t's 4
// phases we stage tile t+2 into slot (t+2)%3 (freed at end of tile t-1).
// vmcnt(6) at phase 3 = exactly tile t+2's loads outstanding.
__global__ __launch_bounds__(512, 2)
void conv_mfma8(const __hip_bfloat16* __restrict__ xs,
                const __hip_bfloat16* __restrict__ wt,
                const float* __restrict__ isg,
                float* __restrict__ out) {
  extern __shared__ __align__(16) char lds[];
  char* ldsA = lds;                  // 3 x 16 KB
  char* ldsB = lds + 3 * SLOTA;      // 3 x 32 KB

  // XCD-aware decode: hardware round-robins blockIdx%8 across XCDs; this
  // mapping puts batches {2k,2k+1} (32 blocks) on one XCD.
  const int bid = blockIdx.x;
  const int lin = (bid & 7) * 32 + (bid >> 3);
  const int b  = lin >> 4;
  const int mt = (lin >> 2) & 3;
  const int nt = lin & 3;
  const int m0  = mt * 128;
  const int hw0 = nt * 256;

  const int t  = threadIdx.x;
  const int wv = t >> 6;
  const int l  = t & 63;
  const int wr = wv >> 2;            // 0..1  M half
  const int wc = wv & 3;             // 0..3  N quarter

  // staging bases (element offsets into the tap-plane / spatial-shifted xs)
  int baseA[2], baseB[4];
  const int swz = (l & 7) ^ (l >> 3);
#pragma unroll
  for (int q = 0; q < 2; ++q) {
    int r = (wv * 2 + q) * 8 + (l >> 3);
    baseA[q] = (m0 + r) * CIN + swz * 8;
  }
#pragma unroll
  for (int q = 0; q < 4; ++q) {
    int r = (wv * 4 + q) * 8 + (l >> 3);
    int n_abs = hw0 + r;
    int hB = n_abs >> 5, wB = n_abs & 31;
    baseB[q] = ((b * HP + hB) * HP + wB) * CIN + swz * 8;
  }

  // ds_read byte offsets (within a slot)
  int offA[2][4], offB[2][4];
#pragma unroll
  for (int kk = 0; kk < 2; ++kk) {
#pragma unroll
    for (int f = 0; f < 4; ++f) {
      int slot16 = ((kk * 4) + (l >> 4)) ^ (l & 7);
      offA[kk][f] = (wr * 64 + f * 16 + (l & 15)) * 128 + slot16 * 16;
      offB[kk][f] = (wc * 64 + f * 16 + (l & 15)) * 128 + slot16 * 16;
    }
  }

  f32x4 acc[4][4];
#pragma unroll
  for (int m = 0; m < 4; ++m)
#pragma unroll
    for (int n = 0; n < 4; ++n)
      acc[m][n] = (f32x4){0.f, 0.f, 0.f, 0.f};

#define TILE_OFFS(tt, gA, gB)                                   \
  {                                                             \
    int tap = (tt) >> 3, ic = (tt) & 7;                         \
    int kh = (tap * 11) >> 5;                                   \
    int kw = tap - kh * 3;                                      \
    gA = tap * (COUT * CIN) + ic * 64;                          \
    gB = (kh * HP + kw) * CIN + ic * 64;                        \
  }

#define STAGE_A(q, gA, sl)                                                  \
  __builtin_amdgcn_global_load_lds(                                         \
      (gvoid*)(const void*)(wt + (gA) + baseA[q]),                          \
      (lvoid*)(ldsA + (sl) * SLOTA + (wv * 2 + (q)) * 1024), 16, 0, 0)
#define STAGE_B(q, gB, sl)                                                  \
  __builtin_amdgcn_global_load_lds(                                         \
      (gvoid*)(const void*)(xs + (gB) + baseB[q]),                          \
      (lvoid*)(ldsB + (sl) * SLOTB + (wv * 4 + (q)) * 1024), 16, 0, 0)

  // prologue: stage tiles 0 and 1
  {
    int gA, gB;
    TILE_OFFS(0, gA, gB);
    STAGE_A(0, gA, 0); STAGE_A(1, gA, 0);
    STAGE_B(0, gB, 0); STAGE_B(1, gB, 0); STAGE_B(2, gB, 0); STAGE_B(3, gB, 0);
    TILE_OFFS(1, gA, gB);
    STAGE_A(0, gA, 1); STAGE_A(1, gA, 1);
    STAGE_B(0, gB, 1); STAGE_B(1, gB, 1); STAGE_B(2, gB, 1); STAGE_B(3, gB, 1);
  }
  asm volatile("s_waitcnt vmcnt(6)" ::: "memory");
  __builtin_amdgcn_s_barrier();

#define PHASE(mp, kk, STAGES)                                                         \
  {                                                                                   \
    bf16x8 af0 = *(const bf16x8*)(pA + offA[kk][2 * (mp)]);                           \
    bf16x8 af1 = *(const bf16x8*)(pA + offA[kk][2 * (mp) + 1]);                       \
    if ((mp) == 0) {                                                                  \
      bfr0 = *(const bf16x8*)(pB + offB[kk][0]);                                      \
      bfr1 = *(const bf16x8*)(pB + offB[kk][1]);                                      \
      bfr2 = *(const bf16x8*)(pB + offB[kk][2]);                                      \
      bfr3 = *(const bf16x8*)(pB + offB[kk][3]);                                      \
    }                                                                                 \
    STAGES;                                                                           \
    __builtin_amdgcn_s_barrier();                                                     \
    __builtin_amdgcn_s_setprio(1);                                                    \
    acc[2*(mp)][0]   = __builtin_amdgcn_mfma_f32_16x16x32_bf16(af0, bfr0, acc[2*(mp)][0],   0,0,0); \
    acc[2*(mp)][1]   = __builtin_amdgcn_mfma_f32_16x16x32_bf16(af0, bfr1, acc[2*(mp)][1],   0,0,0); \
    acc[2*(mp)][2]   = __builtin_amdgcn_mfma_f32_16x16x32_bf16(af0, bfr2, acc[2*(mp)][2],   0,0,0); \
    acc[2*(mp)][3]   = __builtin_amdgcn_mfma_f32_16x16x32_bf16(af0, bfr3, acc[2*(mp)][3],   0,0,0); \
    acc[2*(mp)+1][0] = __builtin_amdgcn_mfma_f32_16x16x32_bf16(af1, bfr0, acc[2*(mp)+1][0], 0,0,0); \
    acc[2*(mp)+1][1] = __builtin_amdgcn_mfma_f32_16x16x32_bf16(af1, bfr1, acc[2*(mp)+1][1], 0,0,0); \
    acc[2*(mp)+1][2] = __builtin_amdgcn_mfma_f32_16x16x32_bf16(af1, bfr2, acc[2*(mp)+1][2], 0,0,0); \
    acc[2*(mp)+1][3] = __builtin_amdgcn_mfma_f32_16x16x32_bf16(af1, bfr3, acc[2*(mp)+1][3], 0,0,0); \
    __builtin_amdgcn_s_setprio(0);                                                    \
    __builtin_amdgcn_s_barrier();                                                     \
  }

  int cur = 0, s2 = 2;
  bf16x8 bfr0, bfr1, bfr2, bfr3;
  for (int tt = 0; tt < NTILES; ++tt) {
    int t2 = tt + 2;
    if (t2 >= NTILES) t2 = NTILES - 1;     // harmless re-stage into free slot
    int gA2, gB2;
    TILE_OFFS(t2, gA2, gB2);
    const char* pA = ldsA + cur * SLOTA;
    const char* pB = ldsB + cur * SLOTB;

    PHASE(0, 0, { STAGE_A(0, gA2, s2); STAGE_A(1, gA2, s2); });
    PHASE(1, 0, { STAGE_B(0, gB2, s2); STAGE_B(1, gB2, s2); });
    PHASE(0, 1, { STAGE_B(2, gB2, s2); });
    PHASE(1, 1, { STAGE_B(3, gB2, s2);
                  asm volatile("s_waitcnt vmcnt(6)" ::: "memory"); });

    cur = (cur == 2) ? 0 : cur + 1;
    s2  = (s2  == 2) ? 0 : s2  + 1;
  }

  // epilogue: C/D col=l&15 -> hw, row=(l>>4)*4+j -> o
#pragma unroll
  for (int m = 0; m < 4; ++m) {
#pragma unroll
    for (int j = 0; j < 4; ++j) {
      int o = m0 + wr * 64 + m * 16 + (l >> 4) * 4 + j;
      float sg = isg[b * COUT + o];
      float* orow = out + ((size_t)(b * COUT + o)) * HWN + hw0 + wc * 64 + (l & 15);
#pragma unroll
      for (int n = 0; n < 4; ++n)
        orow[n * 16] = acc[m][n][j] * sg;
    }
  }
}

extern "C" void kernel_launch(void* const* d_in, const int* in_sizes, int n_in,
                              void* d_out, int out_size, void* d_ws, size_t ws_size,
                              hipStream_t stream) {
  const float* x = (const float*)d_in[0];
  const float* s = (const float*)d_in[1];
  const float* w = (const float*)d_in[2];
  float* out = (float*)d_out;
  char* ws = (char*)d_ws;
  __hip_bfloat16* xs  = (__hip_bfloat16*)(ws + XS_OFF);
  __hip_bfloat16* wt  = (__hip_bfloat16*)(ws + WT_OFF);
  float*          isg = (float*)(ws + ISG_OFF);

  (void)hipFuncSetAttribute((const void*)conv_mfma8,
                            hipFuncAttributeMaxDynamicSharedMemorySize, LDS_BYTES);

  hipLaunchKernelGGL(wprep, dim3(COUT), dim3(256), 0, stream, w, s, wt, isg);
  hipLaunchKernelGGL(pack3, dim3(BATCH * 34), dim3(256), 0, stream, x, s, xs);
  hipLaunchKernelGGL(conv_mfma8, dim3(256), dim3(512), LDS_BYTES, stream,
                     xs, wt, isg, out);
}